// Round 7
// baseline (1316.898 us; speedup 1.0000x reference)
//
#include <hip/hip_runtime.h>

// ROSA 1-bit layer — wave-parallel suffix automaton, v4 (register-resident tr).
// The suffix-link chain lives one-state-per-lane. Next step's tr words come
// from THIS step's st[q] gather (the images ARE the new chain), patched for
// this step's tr writes via an LDS tag array (complete over all write sets:
// walk, redirect, clone-create, top-create). Only ONE dependent LDS gather
// (st[qe]) remains on the critical path; the tag gather overlaps the tail.

#define B_   2
#define T_   2048
#define C_   128
#define MAXS 4100   // max states = 2T+1 = 4097

typedef unsigned int       u32;
typedef unsigned short     u16;
typedef unsigned long long u64;
typedef u16 __attribute__((may_alias)) u16a;
typedef u32 __attribute__((may_alias)) u32a;

__global__ __launch_bounds__(64)
void rosa_kernel(const float* __restrict__ x,
                 const float* __restrict__ emb0,
                 const float* __restrict__ emb1,
                 float* __restrict__ out)
{
    // st[v]: w0 = transitions (lo16 sym0, hi16 sym1; 0xFFFF = none)
    //        w1 = e (lo16) | (len | f<<15) (hi16), f = x[e+1]
    __shared__ u64 st[MAXS];
    __shared__ u16 tag[MAXS];     // (step<<1)|type for this-step tr writes
    __shared__ u64 bits[T_ / 64];
    __shared__ u64 y2[T_ / 32];   // 2-bit y codes (0:-1, 1:0, 2:1)
    __shared__ u64 scratch[64];

    const int blk  = blockIdx.x;
    const int bb   = blk >> 7;
    const int cc   = blk & (C_ - 1);
    const int lane = threadIdx.x;

    // ---- phase 1: bit packing + tag init ----
    const float* xp = x + (size_t)bb * T_ * C_ + cc;
    for (int k = 0; k < T_ / 64; ++k) {
        float v = xp[(size_t)(k * 64 + lane) * C_];
        u64 m = __ballot(v > 0.0f);
        if (lane == 0) bits[k] = m;
    }
    for (int k = lane; k < MAXS; k += 64) tag[k] = 0xFFFFu;
    __syncthreads();

    u16a* tr16 = (u16a*)st;   // tr16[4*v + t]
    u32a* st32 = (u32a*)st;

    // ---- step 0 (scalar) ----
    u64 curw = bits[0];
    const int t0 = (int)(curw & 1ull);
    const int f0 = (int)((curw >> 1) & 1ull);
    const u32 tr0w = (0xFFFFFFFFu & ~(0xFFFFu << (t0 << 4))) | (1u << (t0 << 4));
    if (lane == 0) {
        st[0] = ((u64)(u32)((0 | (f0 << 15)) << 16) << 32) | tr0w;         // root: e=0,len=0
        st[1] = ((u64)(u32)((1 | (f0 << 15)) << 16) << 32) | 0xFFFFFFFFu;  // e=0,len=1
    }
    __syncthreads();

    // ---- phase 2 ----
    bool act  = (lane == 63);   // root at lane 63; middles sparse in [1..62]
    int  vid  = 0, vlen = 0;
    u32  trv  = tr0w;           // register-resident tr word of my chain state
    int  g = 1, z = 2;
    u64  yacc = 0;              // y[0] = -1 -> code 0 (bits 1:0)
    u64  nxtw = bits[1];

    for (int i = 1; i < T_; ++i) {
        if ((i & 63) == 0) { curw = nxtw; int w = (i >> 6) + 1; nxtw = (w < T_/64) ? bits[w] : 0ull; }
        const int ii = i & 63;
        const int t  = (int)((curw >> ii) & 1ull);
        const int fb = (ii == 63) ? (int)(nxtw & 1ull) : (int)((curw >> (ii + 1)) & 1ull);
        const int sh = t << 4;

        // qj straight from registers (no LDS!)
        const int qj = act ? (int)((trv >> sh) & 0xFFFFu) : 0xFFFF;
        const u64 Am = __ballot(act);
        const u64 hasmask = __ballot(qj != 0xFFFF);
        const bool found  = hasmask != 0ull;
        const int  k      = found ? (int)__builtin_ctzll(hasmask) : 64;
        const int  ks     = k & 63;

        // the one dependent LDS gather + prevq bpermute (overlapped)
        const int qe  = (qj == 0xFFFF) ? 0 : qj;
        const u64 stq = st[qe];
        const u64 below = Am & ((1ull << lane) - 1ull);
        const int pidx  = below ? (63 - __builtin_clzll(below)) : 0;
        const int prevq = __builtin_amdgcn_ds_bpermute(pidx << 2, qj);

        const u32 trq  = (u32)stq;
        const u32 elq  = (u32)(stq >> 32);
        const int lenq = (int)((elq >> 16) & 0x7FFFu);

        const int q      = __builtin_amdgcn_readlane(qj, ks);
        const int lenp   = __builtin_amdgcn_readlane(vlen, ks);
        const int lenq_k = __builtin_amdgcn_readlane(lenq, ks);
        const u32 elq_k  = (u32)__builtin_amdgcn_readlane((int)elq, ks);

        const bool clone = found && (lenp + 1 != lenq_k);
        const int r  = z;
        const int u_ = z + 1;
        z += clone ? 2 : 1;

        // redirect run [k, b0)
        const u64 aboveK = ~((2ull << ks) - 1ull);
        const u64 eqm  = __ballot(qj == q);
        const u64 badm = Am & ~eqm & aboveK;
        const int b0   = badm ? (int)__builtin_ctzll(badm) : 64;
        const bool walkw = act && lane < k;
        const bool redir = clone && act && lane >= k && lane < b0 && (qj == q);

        // LDS tr writes + tag stamps (disjoint address sets)
        if (walkw)     { tr16[4 * vid + t] = (u16)r;  tag[vid] = (u16)((i << 1) | 0); }
        if (lane == 0) { tr16[4 * g + t]   = (u16)r;  tag[g]   = (u16)((i << 1) | 0); }
        if (redir)     { tr16[4 * vid + t] = (u16)u_; tag[vid] = (u16)((i << 1) | 1); }

        // keep/dedupe
        const bool keep = act && lane >= k && (lane == k || qj != prevq);
        const int id_cand  = (clone && lane == ks) ? u_ : qj;
        const int len_cand = (clone && lane == ks) ? (lenp + 1) : lenq;
        const u64 keepm = __ballot(keep);

        // tag gather: my new state's patch (lane k w/ clone reads tag[q] for u's copy)
        const int tga = act ? ((clone && lane == ks) ? q : qe) : 0;
        const u16 tg  = tag[tga];

        // e/f updates for new-chain states (incl. u_ and root's image)
        const u32 efv = (u32)(u16)i | ((u32)(len_cand | (fb << 15)) << 16);
        if (keep) st32[2 * id_cand + 1] = efv;
        if (lane == 0) {
            const u32 w1r = (u32)(u16)i | ((u32)((i + 1) | (fb << 15)) << 16);
            st[r] = ((u64)w1r << 32) | 0xFFFFFFFFu;     // create top r
        }

        // predictor output (2-bit buffered)
        const int a = found ? (int)((elq_k >> 31) & 1u) : -1;
        yacc |= (u64)(u32)(a + 1) << (2 * (i & 31));
        if ((i & 31) == 31) { if (lane == 0) y2[i >> 5] = yacc; yacc = 0; }

        // patch my image's tr word for this step's writes
        const bool tvalid = ((int)(tg >> 1) == i);
        const u32  nslot  = (tg & 1) ? (u32)u_ : (u32)r;
        u32 trvn = trq;
        if (tvalid) trvn = (trvn & ~(0xFFFFu << sh)) | (nslot << sh);

        // late clone create: lane k holds u's exact post-walk word
        if (clone && lane == ks) {
            const u32 w1u = (u32)(u16)i | ((u32)((lenp + 1) | (fb << 15)) << 16);
            st[u_] = ((u64)w1u << 32) | trvn;
        }

        // root-image broadcast (for newpos insertion)
        const int sId  = __builtin_amdgcn_readlane(id_cand, 63);
        const int sLen = __builtin_amdgcn_readlane(len_cand, 63);
        const u32 sW   = (u32)__builtin_amdgcn_readlane((int)trvn, 63);

        // ---- new sparse chain ----
        const bool k63 = (keepm >> 63) & 1ull;
        const u64  kmid = keepm & 0x7FFFFFFFFFFFFFFFull;
        const int  P = kmid ? (63 - __builtin_clzll(kmid)) : 0;
        const int  newpos = P + 1;
        const bool recomp = k63 && (newpos >= 63);

        bool actn = keep && lane < 63;
        int  idn  = actn ? id_cand : 0;
        int  lenn = actn ? len_cand : 0;
        u32  trvn2 = trvn;
        if (k63 && !recomp && lane == newpos) { actn = true; idn = sId; lenn = sLen; trvn2 = sW; }
        if (recomp) {                          // rare dense repack (incl. tr words)
            const int dest = 1 + (int)__builtin_popcountll(keepm & ((1ull << lane) - 1ull));
            if (keep) scratch[dest] = (u64)(u16)id_cand | ((u64)(u16)len_cand << 16)
                                    | ((u64)trvn << 32);
            const int cnt = (int)__builtin_popcountll(keepm);
            const u64 sc = scratch[lane];
            const bool inr = (lane >= 1 && lane <= cnt);
            actn = inr;
            idn  = inr ? (int)(sc & 0xFFFFu) : 0;
            lenn = inr ? (int)((sc >> 16) & 0xFFFFu) : 0;
            trvn2 = inr ? (u32)(sc >> 32) : 0u;
        }
        if (lane == 63) {                      // root: local patch, no tag needed
            actn = true; idn = 0; lenn = 0;
            u32 rw = trv;
            if (!found)     rw = (rw & ~(0xFFFFu << sh)) | ((u32)r  << sh);
            else if (redir) rw = (rw & ~(0xFFFFu << sh)) | ((u32)u_ << sh);
            trvn2 = rw;
        }

        act = actn; vid = idn; vlen = lenn; trv = trvn2; g = r;
    }
    __syncthreads();

    // ---- phase 3: select + store ----
    const float e0 = emb0[cc];
    const float e1 = emb1[cc];
    float* op = out + (size_t)bb * T_ * C_ + cc;
    for (int tt = lane; tt < T_; tt += 64) {
        const int code = (int)((y2[tt >> 5] >> (2 * (tt & 31))) & 3ull);
        op[(size_t)tt * C_] = (code == 0) ? 0.0f : (code == 1 ? e0 : e1);
    }
}

extern "C" void kernel_launch(void* const* d_in, const int* in_sizes, int n_in,
                              void* d_out, int out_size, void* d_ws, size_t ws_size,
                              hipStream_t stream)
{
    const float* x    = (const float*)d_in[0];
    const float* emb0 = (const float*)d_in[1];
    const float* emb1 = (const float*)d_in[2];
    float* out = (float*)d_out;

    dim3 grid(B_ * C_);
    dim3 block(64);
    rosa_kernel<<<grid, block, 0, stream>>>(x, emb0, emb1, out);
}